// Round 2
// baseline (6887.266 us; speedup 1.0000x reference)
//
#include <hip/hip_runtime.h>
#include <hip/hip_fp16.h>

#define NB 256
#define NT 512

// ---------------- workspace layout (bytes) ----------------
// 0        cnt region (4096)          -- zeroed via hipMemsetAsync each launch
// 4096     h_enc  [2][2][2048] f32    (32768)
// 36864    h_dec  [2][2][1024] f32    (16384)
// 53248    h0     [2][1024]   f32     (8192)
// 61440    common [512]       f32     (2048)
// 63488    bsum   [2][4096]   f32     (32768)
// 96256    d1     [2][4096]   f32     (32768)
// 129024   embf   [256][1024] f32     (1048576)
// 1177600  P      [2][8192][256] f32  (16777216)   P[dir][row][t]
// 17954816 Wcomb  [2][4096][1024] fp16 (16777216)
// 34732032 WhhE   [8192][2048] fp16   (33554432)
// total fast path: 68286464
//
// R1 post-mortem: bf16 weights gave absmax 4.1e-2 vs 2.77e-2 threshold
// (encoder-chain quantization). fp16 keeps 2-byte traffic (per-XCD L2
// residency: 32 blk x 128KB = 4MB L2) with 8x less rounding error.

struct KArgs {
  const int *x, *Vg, *Jg;
  const float *emb, *embVg, *embJg;
  const float *encWih, *encWhh, *encBih, *encBhh;
  const float *clsW, *clsB, *latfW, *latfB, *latrW, *latrB, *mixW, *mixB;
  const float *recWih[2], *recWhh[2], *recBih[2], *recBhh[2];
  float* out;
  unsigned* cnt;
  float *h_enc, *h_dec, *h0, *common, *bsum, *d1, *embf, *P;
  unsigned short *Wcomb, *WhhE;
  int fast;
};

__device__ __forceinline__ unsigned packh2(float lo, float hi) {
  __half2 h = __floats2half2_rn(lo, hi);
  return *(unsigned*)&h;
}
__device__ __forceinline__ float2 h2f2(unsigned u) {
  __half2 h = *(__half2*)&u;
  return __half22float2(h);
}
__device__ __forceinline__ float sigm(float x) { return 1.f / (1.f + __expf(-x)); }
__device__ __forceinline__ float tanh_(float x) { return 2.f / (1.f + __expf(-2.f * x)) - 1.f; }
__device__ __forceinline__ float wred(float v) {
#pragma unroll
  for (int off = 32; off; off >>= 1) v += __shfl_xor(v, off, 64);
  return v;
}
// agent-scope (device-coherent) accesses: bypass non-coherent per-XCD L2 state,
// so the grid barrier needs no cache-wide invalidation (weights stay cached).
__device__ __forceinline__ void cstoref(float* p, float v) {
  __hip_atomic_store(p, v, __ATOMIC_RELAXED, __HIP_MEMORY_SCOPE_AGENT);
}
__device__ __forceinline__ float cloadf(const float* p) {
  return __hip_atomic_load(p, __ATOMIC_RELAXED, __HIP_MEMORY_SCOPE_AGENT);
}
__device__ __forceinline__ void cstoreu(unsigned* p, unsigned v) {
  __hip_atomic_store(p, v, __ATOMIC_RELAXED, __HIP_MEMORY_SCOPE_AGENT);
}

__device__ __forceinline__ void gbar(unsigned* cnt, unsigned target) {
  __syncthreads();  // all waves' stores drained (compiler emits vmcnt(0) before s_barrier)
  if (threadIdx.x == 0) {
    __hip_atomic_fetch_add(cnt, 1u, __ATOMIC_RELEASE, __HIP_MEMORY_SCOPE_AGENT);
    while (__hip_atomic_load(cnt, __ATOMIC_RELAXED, __HIP_MEMORY_SCOPE_AGENT) < target)
      __builtin_amdgcn_s_sleep(4);
  }
  __syncthreads();
}

__global__ __launch_bounds__(NT, 2) void rnn2_kernel(KArgs a) {
  __shared__ float smem[16384];  // 64 KB, reused per phase
  const int tid = threadIdx.x;
  const int b = blockIdx.x;
  const int wq = __builtin_amdgcn_readfirstlane(tid >> 6);  // wave id, provably uniform
  const int lane = tid & 63;
  unsigned epoch = 0;

  float* out_recf = a.out + 1280;
  float* out_recr = a.out + 1280 + 262144;
  float* out_embf = a.out + 1280 + 2 * 262144;
  float* out_embr = a.out + 1280 + 3 * 262144;

  // ================= phase 0a =================
  // stage emb rows 0 (start) and 1 (stop) into LDS for d1
  for (int i = tid; i < 2048; i += NT) smem[i] = a.emb[i];
  __syncthreads();
  {  // d1[dir][row] = start_vec @ Wih.T + bih + bhh   (dir0: emb[0], dir1: emb[1])
    int wg = b * 8 + wq;
#pragma unroll 1
    for (int rr = 0; rr < 4; rr++) {
      int idx = wg + rr * 2048;
      int dir = idx >> 12;
      int row = idx & 4095;
      const float* Wih = a.recWih[dir];
      const float* sv = &smem[dir * 1024];
      float acc = 0.f;
#pragma unroll
      for (int kc = 0; kc < 4; kc++) {
        int k = kc * 256 + lane * 4;
        float4 wv = *(const float4*)&Wih[row * 1024 + k];
        float4 ev = *(const float4*)&sv[k];
        acc += wv.x * ev.x + wv.y * ev.y + wv.z * ev.z + wv.w * ev.w;
      }
      acc = wred(acc);
      if (lane == 0)
        cstoref(&a.d1[dir * 4096 + row], acc + a.recBih[dir][row] + a.recBhh[dir][row]);
    }
  }
  const int gtid = b * NT + tid;
  const int GSZ = NB * NT;
  // emb gather -> ws (coherent) + outputs emb_f / emb_r
  for (int i = gtid; i < 256 * 1024; i += GSZ) {
    int t = i >> 10, e = i & 1023;
    float v = a.emb[a.x[t] * 1024 + e];
    cstoref(&a.embf[i], v);
    out_embf[i] = v;
    out_embr[(255 - t) * 1024 + e] = v;
  }
  // rec edge rows: rec_f[0]=emb[1], rec_f[255]=emb[0]; rec_r[0]=emb[0], rec_r[255]=emb[1]
  if (gtid < 1024) {
    int e = gtid;
    out_recf[e] = a.emb[1024 + e];
    out_recf[255 * 1024 + e] = a.emb[e];
    out_recr[e] = a.emb[e];
    out_recr[255 * 1024 + e] = a.emb[1024 + e];
  }
  if (gtid < 4096) cstoref(&a.h_enc[gtid], 0.f);  // h0 = c0 = 0 (buffer 0)
  if (gtid < 8192) {
    int dir = gtid >> 12, r = gtid & 4095;
    cstoref(&a.bsum[gtid], a.recBih[dir][r] + a.recBhh[dir][r]);
  }
  if (a.fast) {
    unsigned* W32 = (unsigned*)a.WhhE;
    const int N4 = 8192 * 2048 / 4;
    for (int i = gtid; i < N4; i += GSZ) {
      float4 v = *(const float4*)&a.encWhh[(size_t)i * 4];
      cstoreu(&W32[i * 2], packh2(v.x, v.y));
      cstoreu(&W32[i * 2 + 1], packh2(v.z, v.w));
    }
    unsigned* C32 = (unsigned*)a.Wcomb;
    const int M4 = 4096 * 1024 / 4;
    for (int i = gtid; i < 2 * M4; i += GSZ) {
      int dir = (i >= M4) ? 1 : 0;
      int j = i - dir * M4;
      float4 va = *(const float4*)&a.recWih[dir][(size_t)j * 4];
      float4 vb = *(const float4*)&a.recWhh[dir][(size_t)j * 4];
      cstoreu(&C32[(size_t)dir * (M4 * 2) + j * 2], packh2(va.x + vb.x, va.y + vb.y));
      cstoreu(&C32[(size_t)dir * (M4 * 2) + j * 2 + 1], packh2(va.z + vb.z, va.w + vb.w));
    }
  }
  gbar(a.cnt, ++epoch * NB);

  // ================= phase 0b: P GEMM =================
  // P[dir][row][t] = emb_{dir}[t] @ encWih.T + encBih + encBhh
  {
    const int tdb = b & 7;
    const int rb = (b >> 3) * 256;
    const int td = tdb * 64 + lane;  // 0..511 : dir-major t columns
    const int dirc = td >> 8;
    const int tcol = td & 255;
    float acc[2][16];
#pragma unroll
    for (int p = 0; p < 2; p++)
#pragma unroll
      for (int r = 0; r < 16; r++) acc[p][r] = 0.f;
    // staging mapping: 8 threads per td-row, coalesced along k
    const int s_td = tid >> 3;
    const int s_j = tid & 7;
    int std_ = tdb * 64 + s_td;
    int st = std_ & 255;
    const float* s_esrc = &a.embf[((std_ >> 8) ? (255 - st) : st) * 1024];
#pragma unroll 1
    for (int kc = 0; kc < 4; kc++) {
      __syncthreads();
#pragma unroll
      for (int m = 0; m < 8; m++) {
        int kk = s_j * 32 + m * 4;
        float4 v = *(const float4*)&s_esrc[kc * 256 + kk];
        smem[(kk + 0) * 64 + s_td] = v.x;
        smem[(kk + 1) * 64 + s_td] = v.y;
        smem[(kk + 2) * 64 + s_td] = v.z;
        smem[(kk + 3) * 64 + s_td] = v.w;
      }
      __syncthreads();
#pragma unroll
      for (int p = 0; p < 2; p++) {
        int row0 = rb + wq * 32 + p * 16;
#pragma unroll 1
        for (int k4 = 0; k4 < 64; k4++) {
          float e0 = smem[(k4 * 4 + 0) * 64 + lane];
          float e1 = smem[(k4 * 4 + 1) * 64 + lane];
          float e2 = smem[(k4 * 4 + 2) * 64 + lane];
          float e3 = smem[(k4 * 4 + 3) * 64 + lane];
#pragma unroll
          for (int r = 0; r < 16; r++) {
            const float* wp = &a.encWih[(size_t)(row0 + r) * 1024 + kc * 256 + k4 * 4];
            float w0 = wp[0], w1 = wp[1], w2 = wp[2], w3 = wp[3];  // uniform -> s_load
            acc[p][r] = fmaf(e0, w0, fmaf(e1, w1, fmaf(e2, w2, fmaf(e3, w3, acc[p][r]))));
          }
        }
      }
    }
#pragma unroll
    for (int p = 0; p < 2; p++)
#pragma unroll
      for (int r = 0; r < 16; r++) {
        int row = rb + wq * 32 + p * 16 + r;
        float bias = a.encBih[row] + a.encBhh[row];
        cstoref(&a.P[(size_t)(dirc * 8192 + row) * 256 + tcol], acc[p][r] + bias);
      }
  }
  gbar(a.cnt, ++epoch * NB);

  // ================= encoder: 256 steps =================
  {
    const int u = b * 8 + wq;  // unit 0..2047, both dirs handled by this wave
    float cf = 0.f, cr = 0.f;  // cell state, redundant in all lanes
#pragma unroll 1
    for (int t = 0; t < 256; t++) {
      float* hbuf = &a.h_enc[(t & 1) * 4096];
      for (int i = tid; i < 4096; i += NT) smem[i] = cloadf(&hbuf[i]);
      __syncthreads();
      float af[4] = {0, 0, 0, 0}, ar[4] = {0, 0, 0, 0};
      if (a.fast) {
#pragma unroll 1
        for (int kc = 0; kc < 4; kc++) {
          int k = kc * 512 + lane * 4;
          float4 hfa = *(const float4*)&smem[k];
          float4 hfb = *(const float4*)&smem[k + 256];
          float4 hra = *(const float4*)&smem[2048 + k];
          float4 hrb = *(const float4*)&smem[2048 + k + 256];
#pragma unroll
          for (int g = 0; g < 4; g++) {
            size_t ro = (size_t)(g * 2048 + u) * 2048;
            uint2 wa = *(const uint2*)&a.WhhE[ro + k];
            uint2 wb = *(const uint2*)&a.WhhE[ro + k + 256];
            float2 w01 = h2f2(wa.x), w23 = h2f2(wa.y);
            float2 w45 = h2f2(wb.x), w67 = h2f2(wb.y);
            af[g] += w01.x * hfa.x + w01.y * hfa.y + w23.x * hfa.z + w23.y * hfa.w +
                     w45.x * hfb.x + w45.y * hfb.y + w67.x * hfb.z + w67.y * hfb.w;
            ar[g] += w01.x * hra.x + w01.y * hra.y + w23.x * hra.z + w23.y * hra.w +
                     w45.x * hrb.x + w45.y * hrb.y + w67.x * hrb.z + w67.y * hrb.w;
          }
        }
      } else {
#pragma unroll 1
        for (int kc = 0; kc < 8; kc++) {
          int k = kc * 256 + lane * 4;
          float4 hf = *(const float4*)&smem[k];
          float4 hr = *(const float4*)&smem[2048 + k];
#pragma unroll
          for (int g = 0; g < 4; g++) {
            float4 wv = *(const float4*)&a.encWhh[(size_t)(g * 2048 + u) * 2048 + k];
            af[g] += wv.x * hf.x + wv.y * hf.y + wv.z * hf.z + wv.w * hf.w;
            ar[g] += wv.x * hr.x + wv.y * hr.y + wv.z * hr.z + wv.w * hr.w;
          }
        }
      }
#pragma unroll
      for (int g = 0; g < 4; g++) { af[g] = wred(af[g]); ar[g] = wred(ar[g]); }
      float pf[4], pr[4];
#pragma unroll
      for (int g = 0; g < 4; g++) {
        pf[g] = a.P[(size_t)(0 * 8192 + g * 2048 + u) * 256 + t];  // uniform s_load, sL1-hot
        pr[g] = a.P[(size_t)(1 * 8192 + g * 2048 + u) * 256 + t];
      }
      float gi = af[0] + pf[0], gf = af[1] + pf[1], gg = af[2] + pf[2], go = af[3] + pf[3];
      cf = sigm(gf) * cf + sigm(gi) * tanh_(gg);
      float hfv = sigm(go) * tanh_(cf);
      gi = ar[0] + pr[0]; gf = ar[1] + pr[1]; gg = ar[2] + pr[2]; go = ar[3] + pr[3];
      cr = sigm(gf) * cr + sigm(gi) * tanh_(gg);
      float hrv = sigm(go) * tanh_(cr);
      float* nbuf = &a.h_enc[((t + 1) & 1) * 4096];
      if (lane == 0) { cstoref(&nbuf[u], hfv); cstoref(&nbuf[2048 + u], hrv); }
      gbar(a.cnt, ++epoch * NB);
    }
  }

  // ================= latents =================
  {
    float* hbuf = &a.h_enc[0];  // final buffer after 256 steps
    for (int i = tid; i < 4096; i += NT) smem[i] = cloadf(&hbuf[i]);
    __syncthreads();
    int wg = b * 8 + wq;
    if (wg < 512) {  // common = tanh([hf,hr] @ cls_W.T + cls_b)
      int r = wg;
      float acc = 0.f;
#pragma unroll 1
      for (int kc = 0; kc < 16; kc++) {
        int k = kc * 256 + lane * 4;
        float4 wv = *(const float4*)&a.clsW[(size_t)r * 4096 + k];
        float4 hv = *(const float4*)&smem[k];
        acc += wv.x * hv.x + wv.y * hv.y + wv.z * hv.z + wv.w * hv.w;
      }
      acc = wred(acc);
      if (lane == 0) cstoref(&a.common[r], tanh_(acc + a.clsB[r]));
    } else if (wg < 1024) {  // lat_f
      int r = wg - 512;
      float acc = 0.f;
#pragma unroll 1
      for (int kc = 0; kc < 8; kc++) {
        int k = kc * 256 + lane * 4;
        float4 wv = *(const float4*)&a.latfW[(size_t)r * 2048 + k];
        float4 hv = *(const float4*)&smem[k];
        acc += wv.x * hv.x + wv.y * hv.y + wv.z * hv.z + wv.w * hv.w;
      }
      acc = wred(acc);
      if (lane == 0) {
        float v = acc + a.latfB[r];
        cstoref(&a.h0[64 + r], v);
        a.out[64 + r] = v;
      }
    } else if (wg < 1536) {  // lat_r
      int r = wg - 1024;
      float acc = 0.f;
#pragma unroll 1
      for (int kc = 0; kc < 8; kc++) {
        int k = kc * 256 + lane * 4;
        float4 wv = *(const float4*)&a.latrW[(size_t)r * 2048 + k];
        float4 hv = *(const float4*)&smem[2048 + k];
        acc += wv.x * hv.x + wv.y * hv.y + wv.z * hv.z + wv.w * hv.w;
      }
      acc = wred(acc);
      if (lane == 0) {
        float v = acc + a.latrB[r];
        cstoref(&a.h0[1024 + 64 + r], v);
        a.out[640 + 64 + r] = v;
      }
    } else if (wg == 1536) {  // vg
      float v = a.embVg[a.Vg[0] * 64 + lane];
      cstoref(&a.h0[lane], v);
      cstoref(&a.h0[1024 + lane], v);
      a.out[lane] = v;
      a.out[640 + lane] = v;
    } else if (wg == 1537) {  // jg
      float v = a.embJg[a.Jg[0] * 64 + lane];
      cstoref(&a.h0[576 + lane], v);
      cstoref(&a.h0[1024 + 576 + lane], v);
      a.out[576 + lane] = v;
      a.out[640 + 576 + lane] = v;
    }
    gbar(a.cnt, ++epoch * NB);
    // mix = common @ mix_W.T + mix_b  -> h0[:,640:1024]
    for (int i = tid; i < 512; i += NT) smem[i] = cloadf(&a.common[i]);
    __syncthreads();
    if (wg < 384) {
      int r = wg;
      float acc = 0.f;
#pragma unroll
      for (int kc = 0; kc < 2; kc++) {
        int k = kc * 256 + lane * 4;
        float4 wv = *(const float4*)&a.mixW[(size_t)r * 512 + k];
        float4 hv = *(const float4*)&smem[k];
        acc += wv.x * hv.x + wv.y * hv.y + wv.z * hv.z + wv.w * hv.w;
      }
      acc = wred(acc);
      if (lane == 0) {
        float v = acc + a.mixB[r];
        cstoref(&a.h0[640 + r], v);
        cstoref(&a.h0[1024 + 640 + r], v);
      }
    }
    gbar(a.cnt, ++epoch * NB);
  }

  // ================= decoders: 254 steps each, both dirs in parallel =================
  {
    const int dir = b & 1;
    const int u = (b >> 1) * 8 + wq;  // 0..1023
    float* outrec = dir ? out_recr : out_recf;
    const unsigned short* Wc = a.Wcomb + (size_t)dir * 4096 * 1024;
    float c = 0.f;
#pragma unroll 1
    for (int s = 1; s <= 254; s++) {
      const float* hsrc = (s == 1) ? &a.h0[dir * 1024]
                                   : &a.h_dec[((s - 1) & 1) * 2048 + dir * 1024];
      for (int i = tid; i < 1024; i += NT) smem[i] = cloadf(&hsrc[i]);
      __syncthreads();
      float acc[4] = {0, 0, 0, 0};
      if (s == 1) {  // g = d1 + h0 @ Whh.T  (f32 weights, one step)
        const float* Whh = a.recWhh[dir];
#pragma unroll 1
        for (int kc = 0; kc < 4; kc++) {
          int k = kc * 256 + lane * 4;
          float4 hv = *(const float4*)&smem[k];
#pragma unroll
          for (int g = 0; g < 4; g++) {
            float4 wv = *(const float4*)&Whh[(size_t)(g * 1024 + u) * 1024 + k];
            acc[g] += wv.x * hv.x + wv.y * hv.y + wv.z * hv.z + wv.w * hv.w;
          }
        }
      } else if (a.fast) {  // g = h @ (Wih+Whh).T + bsum
#pragma unroll 1
        for (int kc = 0; kc < 2; kc++) {
          int k = kc * 512 + lane * 4;
          float4 ha = *(const float4*)&smem[k];
          float4 hb = *(const float4*)&smem[k + 256];
#pragma unroll
          for (int g = 0; g < 4; g++) {
            size_t ro = (size_t)(g * 1024 + u) * 1024;
            uint2 wa = *(const uint2*)&Wc[ro + k];
            uint2 wb = *(const uint2*)&Wc[ro + k + 256];
            float2 w01 = h2f2(wa.x), w23 = h2f2(wa.y);
            float2 w45 = h2f2(wb.x), w67 = h2f2(wb.y);
            acc[g] += w01.x * ha.x + w01.y * ha.y + w23.x * ha.z + w23.y * ha.w +
                      w45.x * hb.x + w45.y * hb.y + w67.x * hb.z + w67.y * hb.w;
          }
        }
      } else {
        const float* Wi = a.recWih[dir];
        const float* Wh = a.recWhh[dir];
#pragma unroll 1
        for (int kc = 0; kc < 4; kc++) {
          int k = kc * 256 + lane * 4;
          float4 hv = *(const float4*)&smem[k];
#pragma unroll
          for (int g = 0; g < 4; g++) {
            size_t ro = (size_t)(g * 1024 + u) * 1024 + k;
            float4 va = *(const float4*)&Wi[ro];
            float4 vb = *(const float4*)&Wh[ro];
            acc[g] += (va.x + vb.x) * hv.x + (va.y + vb.y) * hv.y +
                      (va.z + vb.z) * hv.z + (va.w + vb.w) * hv.w;
          }
        }
      }
#pragma unroll
      for (int g = 0; g < 4; g++) acc[g] = wred(acc[g]);
      const float* bsrc = (s == 1) ? &a.d1[dir * 4096] : &a.bsum[dir * 4096];
      float gi = acc[0] + bsrc[u], gf = acc[1] + bsrc[1024 + u];
      float gg = acc[2] + bsrc[2048 + u], go = acc[3] + bsrc[3072 + u];
      if (s == 1) c = smem[u];  // c0 = h0
      c = sigm(gf) * c + sigm(gi) * tanh_(gg);
      float h2 = sigm(go) * tanh_(c);
      if (lane == 0) {
        cstoref(&a.h_dec[(s & 1) * 2048 + dir * 1024 + u], h2);
        outrec[(size_t)(255 - s) * 1024 + u] = h2;  // ys[s-1] -> rec[254-(s-1)]
      }
      gbar(a.cnt, ++epoch * NB);
    }
  }
}

extern "C" void kernel_launch(void* const* d_in, const int* in_sizes, int n_in,
                              void* d_out, int out_size, void* d_ws, size_t ws_size,
                              hipStream_t stream) {
  (void)in_sizes; (void)n_in; (void)out_size;
  KArgs a;
  a.x = (const int*)d_in[0];
  a.Vg = (const int*)d_in[1];
  a.Jg = (const int*)d_in[2];
  a.emb = (const float*)d_in[3];
  a.embVg = (const float*)d_in[4];
  a.embJg = (const float*)d_in[5];
  a.encWih = (const float*)d_in[6];
  a.encWhh = (const float*)d_in[7];
  a.encBih = (const float*)d_in[8];
  a.encBhh = (const float*)d_in[9];
  a.clsW = (const float*)d_in[10];
  a.clsB = (const float*)d_in[11];
  a.latfW = (const float*)d_in[12];
  a.latfB = (const float*)d_in[13];
  a.latrW = (const float*)d_in[14];
  a.latrB = (const float*)d_in[15];
  a.mixW = (const float*)d_in[16];
  a.mixB = (const float*)d_in[17];
  a.recWih[0] = (const float*)d_in[18];
  a.recWhh[0] = (const float*)d_in[19];
  a.recBih[0] = (const float*)d_in[20];
  a.recBhh[0] = (const float*)d_in[21];
  a.recWih[1] = (const float*)d_in[22];
  a.recWhh[1] = (const float*)d_in[23];
  a.recBih[1] = (const float*)d_in[24];
  a.recBhh[1] = (const float*)d_in[25];
  a.out = (float*)d_out;
  char* ws = (char*)d_ws;
  a.cnt = (unsigned*)ws;
  a.h_enc = (float*)(ws + 4096);
  a.h_dec = (float*)(ws + 36864);
  a.h0 = (float*)(ws + 53248);
  a.common = (float*)(ws + 61440);
  a.bsum = (float*)(ws + 63488);
  a.d1 = (float*)(ws + 96256);
  a.embf = (float*)(ws + 129024);
  a.P = (float*)(ws + 1177600);
  a.Wcomb = (unsigned short*)(ws + 17954816);
  a.WhhE = (unsigned short*)(ws + 34732032);
  a.fast = (ws_size >= 68286464ULL) ? 1 : 0;
  hipMemsetAsync(d_ws, 0, 4096, stream);  // zero the barrier counter each launch
  hipLaunchKernelGGL(rnn2_kernel, dim3(NB), dim3(NT), 0, stream, a);
}

// Round 3
// 3630.757 us; speedup vs baseline: 1.8969x; 1.8969x over previous
//
#include <hip/hip_runtime.h>
#include <hip/hip_fp16.h>

#define NB 256
#define NT 512

// ---------------- workspace layout (bytes) ----------------
// 0        legacy cnt region (4096)   -- zeroed each launch (compact-barrier fallback)
// 4096     h_enc  [2][2][2048] f32    (32768)
// 36864    h_dec  [2][2][1024] f32    (16384)
// 53248    h0     [2][1024]   f32     (8192)
// 61440    common [512]       f32     (2048)
// 63488    bsum   [2][4096]   f32     (32768)
// 96256    d1     [2][4096]   f32     (32768)
// 129024   embf   [256][1024] f32     (1048576)
// 1177600  P      [2][8192][256] f32  (16777216)   P[dir][row][t]
// 17954816 Wcomb  [2][4096][1024] fp16 (16777216)
// 34732032 WhhE   [8192][2048] fp16   (33554432)
// 68286464 barrier trees (12288)      -- zeroed each launch (fast layout)
//
// R2 post-mortem: 13.1 us/step with 256 serialized same-line atomic RMWs +
// 256 pollers on the same line. R3: tree barrier (32 leaves -> root -> flag),
// relaxed atomics only, split fwd/rev decoder barriers, u64 coherent staging.

struct KArgs {
  const int *x, *Vg, *Jg;
  const float *emb, *embVg, *embJg;
  const float *encWih, *encWhh, *encBih, *encBhh;
  const float *clsW, *clsB, *latfW, *latfB, *latrW, *latrB, *mixW, *mixB;
  const float *recWih[2], *recWhh[2], *recBih[2], *recBhh[2];
  float* out;
  unsigned *barFull, *barF, *barR;  // tree bases
  int ls;                           // leaf stride in uints (32 fast / 8 compact)
  float *h_enc, *h_dec, *h0, *common, *bsum, *d1, *embf, *P;
  unsigned short *Wcomb, *WhhE;
  int fast;
};

__device__ __forceinline__ unsigned packh2(float lo, float hi) {
  __half2 h = __floats2half2_rn(lo, hi);
  return *(unsigned*)&h;
}
__device__ __forceinline__ float2 h2f2(unsigned u) {
  __half2 h = *(__half2*)&u;
  return __half22float2(h);
}
__device__ __forceinline__ float sigm(float x) { return 1.f / (1.f + __expf(-x)); }
__device__ __forceinline__ float tanh_(float x) { return 2.f / (1.f + __expf(-2.f * x)) - 1.f; }
__device__ __forceinline__ float wred(float v) {
#pragma unroll
  for (int off = 32; off; off >>= 1) v += __shfl_xor(v, off, 64);
  return v;
}
// agent-scope (device-coherent) accesses: bypass non-coherent per-XCD L2 state,
// so the grid barrier needs no cache-wide invalidation (weights stay cached).
__device__ __forceinline__ void cstoref(float* p, float v) {
  __hip_atomic_store(p, v, __ATOMIC_RELAXED, __HIP_MEMORY_SCOPE_AGENT);
}
__device__ __forceinline__ float cloadf(const float* p) {
  return __hip_atomic_load(p, __ATOMIC_RELAXED, __HIP_MEMORY_SCOPE_AGENT);
}
__device__ __forceinline__ unsigned long long cload64(const unsigned long long* p) {
  return __hip_atomic_load(p, __ATOMIC_RELAXED, __HIP_MEMORY_SCOPE_AGENT);
}
__device__ __forceinline__ void cstoreu(unsigned* p, unsigned v) {
  __hip_atomic_store(p, v, __ATOMIC_RELAXED, __HIP_MEMORY_SCOPE_AGENT);
}

// Tree barrier: groups of 8 blocks -> leaf; last of group -> root; last at
// root -> flag=epoch. All RELAXED: ordering comes from the vmcnt(0) drain at
// __syncthreads (coherent sc0/sc1 data stores are complete at the coherence
// point before the arrival add is issued).
__device__ __forceinline__ void gbar_tree(unsigned* tree, int nGroups, int idx,
                                          unsigned e, int ls) {
  __syncthreads();
  if (threadIdx.x == 0) {
    unsigned* leaf = tree + (idx >> 3) * ls;
    unsigned* root = tree + nGroups * ls;
    unsigned* flag = root + ls;
    unsigned old = __hip_atomic_fetch_add(leaf, 1u, __ATOMIC_RELAXED, __HIP_MEMORY_SCOPE_AGENT);
    if (old == e * 8u - 1u) {
      unsigned ro = __hip_atomic_fetch_add(root, 1u, __ATOMIC_RELAXED, __HIP_MEMORY_SCOPE_AGENT);
      if (ro == e * (unsigned)nGroups - 1u)
        __hip_atomic_store(flag, e, __ATOMIC_RELAXED, __HIP_MEMORY_SCOPE_AGENT);
    }
    while (__hip_atomic_load(flag, __ATOMIC_RELAXED, __HIP_MEMORY_SCOPE_AGENT) < e)
      __builtin_amdgcn_s_sleep(2);
  }
  __syncthreads();
}

__global__ __launch_bounds__(NT, 2) void rnn2_kernel(KArgs a) {
  __shared__ float smem[16384];  // 64 KB, reused per phase
  const int tid = threadIdx.x;
  const int b = blockIdx.x;
  const int wq = __builtin_amdgcn_readfirstlane(tid >> 6);  // wave id, provably uniform
  const int lane = tid & 63;
  unsigned epoch = 0;

  float* out_recf = a.out + 1280;
  float* out_recr = a.out + 1280 + 262144;
  float* out_embf = a.out + 1280 + 2 * 262144;
  float* out_embr = a.out + 1280 + 3 * 262144;

  // ================= phase 0a =================
  // stage emb rows 0 (start) and 1 (stop) into LDS for d1
  for (int i = tid; i < 2048; i += NT) smem[i] = a.emb[i];
  __syncthreads();
  {  // d1[dir][row] = start_vec @ Wih.T + bih + bhh   (dir0: emb[0], dir1: emb[1])
    int wg = b * 8 + wq;
#pragma unroll 1
    for (int rr = 0; rr < 4; rr++) {
      int idx = wg + rr * 2048;
      int dir = idx >> 12;
      int row = idx & 4095;
      const float* Wih = a.recWih[dir];
      const float* sv = &smem[dir * 1024];
      float acc = 0.f;
#pragma unroll
      for (int kc = 0; kc < 4; kc++) {
        int k = kc * 256 + lane * 4;
        float4 wv = *(const float4*)&Wih[row * 1024 + k];
        float4 ev = *(const float4*)&sv[k];
        acc += wv.x * ev.x + wv.y * ev.y + wv.z * ev.z + wv.w * ev.w;
      }
      acc = wred(acc);
      if (lane == 0)
        cstoref(&a.d1[dir * 4096 + row], acc + a.recBih[dir][row] + a.recBhh[dir][row]);
    }
  }
  const int gtid = b * NT + tid;
  const int GSZ = NB * NT;
  // emb gather -> ws (coherent) + outputs emb_f / emb_r
  for (int i = gtid; i < 256 * 1024; i += GSZ) {
    int t = i >> 10, e = i & 1023;
    float v = a.emb[a.x[t] * 1024 + e];
    cstoref(&a.embf[i], v);
    out_embf[i] = v;
    out_embr[(255 - t) * 1024 + e] = v;
  }
  // rec edge rows: rec_f[0]=emb[1], rec_f[255]=emb[0]; rec_r[0]=emb[0], rec_r[255]=emb[1]
  if (gtid < 1024) {
    int e = gtid;
    out_recf[e] = a.emb[1024 + e];
    out_recf[255 * 1024 + e] = a.emb[e];
    out_recr[e] = a.emb[e];
    out_recr[255 * 1024 + e] = a.emb[1024 + e];
  }
  if (gtid < 4096) cstoref(&a.h_enc[gtid], 0.f);  // h0 = c0 = 0 (buffer 0)
  if (gtid < 8192) {
    int dir = gtid >> 12, r = gtid & 4095;
    cstoref(&a.bsum[gtid], a.recBih[dir][r] + a.recBhh[dir][r]);
  }
  if (a.fast) {
    unsigned* W32 = (unsigned*)a.WhhE;
    const int N4 = 8192 * 2048 / 4;
    for (int i = gtid; i < N4; i += GSZ) {
      float4 v = *(const float4*)&a.encWhh[(size_t)i * 4];
      cstoreu(&W32[i * 2], packh2(v.x, v.y));
      cstoreu(&W32[i * 2 + 1], packh2(v.z, v.w));
    }
    unsigned* C32 = (unsigned*)a.Wcomb;
    const int M4 = 4096 * 1024 / 4;
    for (int i = gtid; i < 2 * M4; i += GSZ) {
      int dir = (i >= M4) ? 1 : 0;
      int j = i - dir * M4;
      float4 va = *(const float4*)&a.recWih[dir][(size_t)j * 4];
      float4 vb = *(const float4*)&a.recWhh[dir][(size_t)j * 4];
      cstoreu(&C32[(size_t)dir * (M4 * 2) + j * 2], packh2(va.x + vb.x, va.y + vb.y));
      cstoreu(&C32[(size_t)dir * (M4 * 2) + j * 2 + 1], packh2(va.z + vb.z, va.w + vb.w));
    }
  }
  gbar_tree(a.barFull, 32, b, ++epoch, a.ls);

  // ================= phase 0b: P GEMM =================
  // P[dir][row][t] = emb_{dir}[t] @ encWih.T + encBih + encBhh
  {
    const int tdb = b & 7;
    const int rb = (b >> 3) * 256;
    const int td = tdb * 64 + lane;  // 0..511 : dir-major t columns
    const int dirc = td >> 8;
    const int tcol = td & 255;
    float acc[2][16];
#pragma unroll
    for (int p = 0; p < 2; p++)
#pragma unroll
      for (int r = 0; r < 16; r++) acc[p][r] = 0.f;
    // staging mapping: 8 threads per td-row, coalesced along k
    const int s_td = tid >> 3;
    const int s_j = tid & 7;
    int std_ = tdb * 64 + s_td;
    int st = std_ & 255;
    const float* s_esrc = &a.embf[((std_ >> 8) ? (255 - st) : st) * 1024];
#pragma unroll 1
    for (int kc = 0; kc < 4; kc++) {
      __syncthreads();
#pragma unroll
      for (int m = 0; m < 8; m++) {
        int kk = s_j * 32 + m * 4;
        float4 v = *(const float4*)&s_esrc[kc * 256 + kk];
        smem[(kk + 0) * 64 + s_td] = v.x;
        smem[(kk + 1) * 64 + s_td] = v.y;
        smem[(kk + 2) * 64 + s_td] = v.z;
        smem[(kk + 3) * 64 + s_td] = v.w;
      }
      __syncthreads();
#pragma unroll
      for (int p = 0; p < 2; p++) {
        int row0 = rb + wq * 32 + p * 16;
#pragma unroll 1
        for (int k4 = 0; k4 < 64; k4++) {
          float e0 = smem[(k4 * 4 + 0) * 64 + lane];
          float e1 = smem[(k4 * 4 + 1) * 64 + lane];
          float e2 = smem[(k4 * 4 + 2) * 64 + lane];
          float e3 = smem[(k4 * 4 + 3) * 64 + lane];
#pragma unroll
          for (int r = 0; r < 16; r++) {
            const float* wp = &a.encWih[(size_t)(row0 + r) * 1024 + kc * 256 + k4 * 4];
            float w0 = wp[0], w1 = wp[1], w2 = wp[2], w3 = wp[3];  // uniform -> s_load
            acc[p][r] = fmaf(e0, w0, fmaf(e1, w1, fmaf(e2, w2, fmaf(e3, w3, acc[p][r]))));
          }
        }
      }
    }
#pragma unroll
    for (int p = 0; p < 2; p++)
#pragma unroll
      for (int r = 0; r < 16; r++) {
        int row = rb + wq * 32 + p * 16 + r;
        float bias = a.encBih[row] + a.encBhh[row];
        cstoref(&a.P[(size_t)(dirc * 8192 + row) * 256 + tcol], acc[p][r] + bias);
      }
  }
  gbar_tree(a.barFull, 32, b, ++epoch, a.ls);

  // ================= encoder: 256 steps =================
  {
    const int u = b * 8 + wq;  // unit 0..2047, both dirs handled by this wave
    float cf = 0.f, cr = 0.f;  // cell state, redundant in all lanes
#pragma unroll 1
    for (int t = 0; t < 256; t++) {
      float* hbuf = &a.h_enc[(t & 1) * 4096];
      {  // wide coherent staging: 4096 f32 = 2048 u64, 4 per thread, pipelined
        const unsigned long long* hb64 = (const unsigned long long*)hbuf;
        unsigned long long* s64 = (unsigned long long*)smem;
        unsigned long long v0 = cload64(&hb64[tid]);
        unsigned long long v1 = cload64(&hb64[tid + 512]);
        unsigned long long v2 = cload64(&hb64[tid + 1024]);
        unsigned long long v3 = cload64(&hb64[tid + 1536]);
        s64[tid] = v0; s64[tid + 512] = v1; s64[tid + 1024] = v2; s64[tid + 1536] = v3;
      }
      __syncthreads();
      float af[4] = {0, 0, 0, 0}, ar[4] = {0, 0, 0, 0};
      if (a.fast) {
#pragma unroll 1
        for (int kc = 0; kc < 4; kc++) {
          int k = kc * 512 + lane * 4;
          float4 hfa = *(const float4*)&smem[k];
          float4 hfb = *(const float4*)&smem[k + 256];
          float4 hra = *(const float4*)&smem[2048 + k];
          float4 hrb = *(const float4*)&smem[2048 + k + 256];
#pragma unroll
          for (int g = 0; g < 4; g++) {
            size_t ro = (size_t)(g * 2048 + u) * 2048;
            uint2 wa = *(const uint2*)&a.WhhE[ro + k];
            uint2 wb = *(const uint2*)&a.WhhE[ro + k + 256];
            float2 w01 = h2f2(wa.x), w23 = h2f2(wa.y);
            float2 w45 = h2f2(wb.x), w67 = h2f2(wb.y);
            af[g] += w01.x * hfa.x + w01.y * hfa.y + w23.x * hfa.z + w23.y * hfa.w +
                     w45.x * hfb.x + w45.y * hfb.y + w67.x * hfb.z + w67.y * hfb.w;
            ar[g] += w01.x * hra.x + w01.y * hra.y + w23.x * hra.z + w23.y * hra.w +
                     w45.x * hrb.x + w45.y * hrb.y + w67.x * hrb.z + w67.y * hrb.w;
          }
        }
      } else {
#pragma unroll 1
        for (int kc = 0; kc < 8; kc++) {
          int k = kc * 256 + lane * 4;
          float4 hf = *(const float4*)&smem[k];
          float4 hr = *(const float4*)&smem[2048 + k];
#pragma unroll
          for (int g = 0; g < 4; g++) {
            float4 wv = *(const float4*)&a.encWhh[(size_t)(g * 2048 + u) * 2048 + k];
            af[g] += wv.x * hf.x + wv.y * hf.y + wv.z * hf.z + wv.w * hf.w;
            ar[g] += wv.x * hr.x + wv.y * hr.y + wv.z * hr.z + wv.w * hr.w;
          }
        }
      }
#pragma unroll
      for (int g = 0; g < 4; g++) { af[g] = wred(af[g]); ar[g] = wred(ar[g]); }
      float pf[4], pr[4];
#pragma unroll
      for (int g = 0; g < 4; g++) {
        pf[g] = a.P[(size_t)(0 * 8192 + g * 2048 + u) * 256 + t];  // uniform s_load, sL1-hot
        pr[g] = a.P[(size_t)(1 * 8192 + g * 2048 + u) * 256 + t];
      }
      float gi = af[0] + pf[0], gf = af[1] + pf[1], gg = af[2] + pf[2], go = af[3] + pf[3];
      cf = sigm(gf) * cf + sigm(gi) * tanh_(gg);
      float hfv = sigm(go) * tanh_(cf);
      gi = ar[0] + pr[0]; gf = ar[1] + pr[1]; gg = ar[2] + pr[2]; go = ar[3] + pr[3];
      cr = sigm(gf) * cr + sigm(gi) * tanh_(gg);
      float hrv = sigm(go) * tanh_(cr);
      float* nbuf = &a.h_enc[((t + 1) & 1) * 4096];
      if (lane == 0) { cstoref(&nbuf[u], hfv); cstoref(&nbuf[2048 + u], hrv); }
      gbar_tree(a.barFull, 32, b, ++epoch, a.ls);
    }
  }

  // ================= latents =================
  {
    float* hbuf = &a.h_enc[0];  // final buffer after 256 steps
    {
      const unsigned long long* hb64 = (const unsigned long long*)hbuf;
      unsigned long long* s64 = (unsigned long long*)smem;
      unsigned long long v0 = cload64(&hb64[tid]);
      unsigned long long v1 = cload64(&hb64[tid + 512]);
      unsigned long long v2 = cload64(&hb64[tid + 1024]);
      unsigned long long v3 = cload64(&hb64[tid + 1536]);
      s64[tid] = v0; s64[tid + 512] = v1; s64[tid + 1024] = v2; s64[tid + 1536] = v3;
    }
    __syncthreads();
    int wg = b * 8 + wq;
    if (wg < 512) {  // common = tanh([hf,hr] @ cls_W.T + cls_b)
      int r = wg;
      float acc = 0.f;
#pragma unroll 1
      for (int kc = 0; kc < 16; kc++) {
        int k = kc * 256 + lane * 4;
        float4 wv = *(const float4*)&a.clsW[(size_t)r * 4096 + k];
        float4 hv = *(const float4*)&smem[k];
        acc += wv.x * hv.x + wv.y * hv.y + wv.z * hv.z + wv.w * hv.w;
      }
      acc = wred(acc);
      if (lane == 0) cstoref(&a.common[r], tanh_(acc + a.clsB[r]));
    } else if (wg < 1024) {  // lat_f
      int r = wg - 512;
      float acc = 0.f;
#pragma unroll 1
      for (int kc = 0; kc < 8; kc++) {
        int k = kc * 256 + lane * 4;
        float4 wv = *(const float4*)&a.latfW[(size_t)r * 2048 + k];
        float4 hv = *(const float4*)&smem[k];
        acc += wv.x * hv.x + wv.y * hv.y + wv.z * hv.z + wv.w * hv.w;
      }
      acc = wred(acc);
      if (lane == 0) {
        float v = acc + a.latfB[r];
        cstoref(&a.h0[64 + r], v);
        a.out[64 + r] = v;
      }
    } else if (wg < 1536) {  // lat_r
      int r = wg - 1024;
      float acc = 0.f;
#pragma unroll 1
      for (int kc = 0; kc < 8; kc++) {
        int k = kc * 256 + lane * 4;
        float4 wv = *(const float4*)&a.latrW[(size_t)r * 2048 + k];
        float4 hv = *(const float4*)&smem[2048 + k];
        acc += wv.x * hv.x + wv.y * hv.y + wv.z * hv.z + wv.w * hv.w;
      }
      acc = wred(acc);
      if (lane == 0) {
        float v = acc + a.latrB[r];
        cstoref(&a.h0[1024 + 64 + r], v);
        a.out[640 + 64 + r] = v;
      }
    } else if (wg == 1536) {  // vg
      float v = a.embVg[a.Vg[0] * 64 + lane];
      cstoref(&a.h0[lane], v);
      cstoref(&a.h0[1024 + lane], v);
      a.out[lane] = v;
      a.out[640 + lane] = v;
    } else if (wg == 1537) {  // jg
      float v = a.embJg[a.Jg[0] * 64 + lane];
      cstoref(&a.h0[576 + lane], v);
      cstoref(&a.h0[1024 + 576 + lane], v);
      a.out[576 + lane] = v;
      a.out[640 + 576 + lane] = v;
    }
    gbar_tree(a.barFull, 32, b, ++epoch, a.ls);
    // mix = common @ mix_W.T + mix_b  -> h0[:,640:1024]
    if (tid < 256) {
      unsigned long long v0 = cload64(&((const unsigned long long*)a.common)[tid]);
      ((unsigned long long*)smem)[tid] = v0;
    }
    __syncthreads();
    if (wg < 384) {
      int r = wg;
      float acc = 0.f;
#pragma unroll
      for (int kc = 0; kc < 2; kc++) {
        int k = kc * 256 + lane * 4;
        float4 wv = *(const float4*)&a.mixW[(size_t)r * 512 + k];
        float4 hv = *(const float4*)&smem[k];
        acc += wv.x * hv.x + wv.y * hv.y + wv.z * hv.z + wv.w * hv.w;
      }
      acc = wred(acc);
      if (lane == 0) {
        float v = acc + a.mixB[r];
        cstoref(&a.h0[640 + r], v);
        cstoref(&a.h0[1024 + 640 + r], v);
      }
    }
    gbar_tree(a.barFull, 32, b, ++epoch, a.ls);
  }

  // ================= decoders: 254 steps each, split fwd/rev barriers =================
  {
    const int dir = b & 1;
    const int hidx = b >> 1;  // 0..127 within my direction's barrier group
    unsigned* btree = dir ? a.barR : a.barF;
    unsigned depoch = 0;
    float* outrec = dir ? out_recr : out_recf;
    const unsigned short* Wc = a.Wcomb + (size_t)dir * 4096 * 1024;
    const int u = hidx * 8 + wq;  // 0..1023
    float c = 0.f;
#pragma unroll 1
    for (int s = 1; s <= 254; s++) {
      const float* hsrc = (s == 1) ? &a.h0[dir * 1024]
                                   : &a.h_dec[((s - 1) & 1) * 2048 + dir * 1024];
      {  // 1024 f32 = 512 u64, one per thread
        unsigned long long v0 = cload64(&((const unsigned long long*)hsrc)[tid]);
        ((unsigned long long*)smem)[tid] = v0;
      }
      __syncthreads();
      float acc[4] = {0, 0, 0, 0};
      if (s == 1) {  // g = d1 + h0 @ Whh.T  (f32 weights, one step)
        const float* Whh = a.recWhh[dir];
#pragma unroll 1
        for (int kc = 0; kc < 4; kc++) {
          int k = kc * 256 + lane * 4;
          float4 hv = *(const float4*)&smem[k];
#pragma unroll
          for (int g = 0; g < 4; g++) {
            float4 wv = *(const float4*)&Whh[(size_t)(g * 1024 + u) * 1024 + k];
            acc[g] += wv.x * hv.x + wv.y * hv.y + wv.z * hv.z + wv.w * hv.w;
          }
        }
      } else if (a.fast) {  // g = h @ (Wih+Whh).T + bsum
#pragma unroll 1
        for (int kc = 0; kc < 2; kc++) {
          int k = kc * 512 + lane * 4;
          float4 ha = *(const float4*)&smem[k];
          float4 hb = *(const float4*)&smem[k + 256];
#pragma unroll
          for (int g = 0; g < 4; g++) {
            size_t ro = (size_t)(g * 1024 + u) * 1024;
            uint2 wa = *(const uint2*)&Wc[ro + k];
            uint2 wb = *(const uint2*)&Wc[ro + k + 256];
            float2 w01 = h2f2(wa.x), w23 = h2f2(wa.y);
            float2 w45 = h2f2(wb.x), w67 = h2f2(wb.y);
            acc[g] += w01.x * ha.x + w01.y * ha.y + w23.x * ha.z + w23.y * ha.w +
                      w45.x * hb.x + w45.y * hb.y + w67.x * hb.z + w67.y * hb.w;
          }
        }
      } else {
        const float* Wi = a.recWih[dir];
        const float* Wh = a.recWhh[dir];
#pragma unroll 1
        for (int kc = 0; kc < 4; kc++) {
          int k = kc * 256 + lane * 4;
          float4 hv = *(const float4*)&smem[k];
#pragma unroll
          for (int g = 0; g < 4; g++) {
            size_t ro = (size_t)(g * 1024 + u) * 1024 + k;
            float4 va = *(const float4*)&Wi[ro];
            float4 vb = *(const float4*)&Wh[ro];
            acc[g] += (va.x + vb.x) * hv.x + (va.y + vb.y) * hv.y +
                      (va.z + vb.z) * hv.z + (va.w + vb.w) * hv.w;
          }
        }
      }
#pragma unroll
      for (int g = 0; g < 4; g++) acc[g] = wred(acc[g]);
      const float* bsrc = (s == 1) ? &a.d1[dir * 4096] : &a.bsum[dir * 4096];
      float gi = acc[0] + bsrc[u], gf = acc[1] + bsrc[1024 + u];
      float gg = acc[2] + bsrc[2048 + u], go = acc[3] + bsrc[3072 + u];
      if (s == 1) c = smem[u];  // c0 = h0
      c = sigm(gf) * c + sigm(gi) * tanh_(gg);
      float h2 = sigm(go) * tanh_(c);
      if (lane == 0) {
        cstoref(&a.h_dec[(s & 1) * 2048 + dir * 1024 + u], h2);
        outrec[(size_t)(255 - s) * 1024 + u] = h2;  // ys[s-1] -> rec[254-(s-1)]
      }
      if (s < 254) gbar_tree(btree, 16, hidx, ++depoch, a.ls);  // skip useless final barrier
    }
  }
}

extern "C" void kernel_launch(void* const* d_in, const int* in_sizes, int n_in,
                              void* d_out, int out_size, void* d_ws, size_t ws_size,
                              hipStream_t stream) {
  (void)in_sizes; (void)n_in; (void)out_size;
  KArgs a;
  a.x = (const int*)d_in[0];
  a.Vg = (const int*)d_in[1];
  a.Jg = (const int*)d_in[2];
  a.emb = (const float*)d_in[3];
  a.embVg = (const float*)d_in[4];
  a.embJg = (const float*)d_in[5];
  a.encWih = (const float*)d_in[6];
  a.encWhh = (const float*)d_in[7];
  a.encBih = (const float*)d_in[8];
  a.encBhh = (const float*)d_in[9];
  a.clsW = (const float*)d_in[10];
  a.clsB = (const float*)d_in[11];
  a.latfW = (const float*)d_in[12];
  a.latfB = (const float*)d_in[13];
  a.latrW = (const float*)d_in[14];
  a.latrB = (const float*)d_in[15];
  a.mixW = (const float*)d_in[16];
  a.mixB = (const float*)d_in[17];
  a.recWih[0] = (const float*)d_in[18];
  a.recWhh[0] = (const float*)d_in[19];
  a.recBih[0] = (const float*)d_in[20];
  a.recBhh[0] = (const float*)d_in[21];
  a.recWih[1] = (const float*)d_in[22];
  a.recWhh[1] = (const float*)d_in[23];
  a.recBih[1] = (const float*)d_in[24];
  a.recBhh[1] = (const float*)d_in[25];
  a.out = (float*)d_out;
  char* ws = (char*)d_ws;
  a.h_enc = (float*)(ws + 4096);
  a.h_dec = (float*)(ws + 36864);
  a.h0 = (float*)(ws + 53248);
  a.common = (float*)(ws + 61440);
  a.bsum = (float*)(ws + 63488);
  a.d1 = (float*)(ws + 96256);
  a.embf = (float*)(ws + 129024);
  a.P = (float*)(ws + 1177600);
  a.Wcomb = (unsigned short*)(ws + 17954816);
  a.WhhE = (unsigned short*)(ws + 34732032);
  const size_t BAR = 68286464ULL;
  a.fast = (ws_size >= BAR + 12288) ? 1 : 0;
  if (a.fast) {
    // fast barrier layout after WhhE: 128B-spaced lines
    a.barFull = (unsigned*)(ws + BAR);               // 32 leaves + root + flag (4608 B)
    a.barF = (unsigned*)(ws + BAR + 4608);           // 16 leaves + root + flag (2304 B)
    a.barR = (unsigned*)(ws + BAR + 4608 + 2432);    // 128-aligned
    a.ls = 32;  // 128 B per counter line
    hipMemsetAsync(ws + BAR, 0, 12288, stream);
  } else {
    // compact fallback inside legacy 4096-B region (32 B spacing)
    a.barFull = (unsigned*)(ws);                     // 32*32 + 64 = 1088 B
    a.barF = (unsigned*)(ws + 1152);                 // 16*32 + 64 = 576 B
    a.barR = (unsigned*)(ws + 1792);
    a.ls = 8;
    hipMemsetAsync(ws, 0, 4096, stream);
  }
  hipLaunchKernelGGL(rnn2_kernel, dim3(NB), dim3(NT), 0, stream, a);
}

// Round 6
// 2558.278 us; speedup vs baseline: 2.6921x; 1.4192x over previous
//
#include <hip/hip_runtime.h>
#include <hip/hip_fp16.h>

#define NB 256
#define NT 512

// ---------------- workspace layout (bytes) ----------------
// 0        barrier region (4096)       -- memset 0 each launch (4 tree barriers)
// 4096     hTenc  u64[2][4096]  65536  -- tagged encoder h (epoch<<32 | f32)
// 69632    hTdec  u64[2][2048]  16384  -- tagged decoder h [buf][dir][1024]
// 86016    common f32[512]      2048   -- plain (barrier-sequenced since R6)
// 90112    bsum   f32[2][4096]  32768
// 122880   d1     f32[2][4096]  32768
// 155648   embf   f32[256][1024] 1048576
// 1204224  P      f32[2][8192][256] 16777216
// 17981440 Wcomb  fp16[2][4096][1024] 16777216
// 34758656 WhhE   fp16[8192][2048] 33554432
// total fast: 68313088
//
// R5 post-mortem: rec_f still failed O(0.5); encoder tagged exchange is
// hardware-proven (outputs 0/1 pass), decoder math proven in R3. R6 isolates
// the barrier-free latent handoff (the only other novel mechanism): latents
// sequenced by tree barriers 3/4 again; tagged loops kept for enc + dec.

struct KArgs {
  const int *x, *Vg, *Jg;
  const float *emb, *embVg, *embJg;
  const float *encWih, *encWhh, *encBih, *encBhh;
  const float *clsW, *clsB, *latfW, *latfB, *latrW, *latrB, *mixW, *mixB;
  const float *recWih[2], *recWhh[2], *recBih[2], *recBhh[2];
  float* out;
  unsigned* barFull;
  unsigned long long *hTenc, *hTdec;
  float *common, *bsum, *d1, *embf, *P;
  unsigned short *Wcomb, *WhhE;
  int fast;
};

__device__ __forceinline__ unsigned packh2(float lo, float hi) {
  __half2 h = __floats2half2_rn(lo, hi);
  return *(unsigned*)&h;
}
__device__ __forceinline__ float2 h2f2(unsigned u) {
  __half2 h = *(__half2*)&u;
  return __half22float2(h);
}
__device__ __forceinline__ unsigned long long packtag(unsigned tag, float f) {
  return ((unsigned long long)tag << 32) | (unsigned long long)__float_as_uint(f);
}
__device__ __forceinline__ float sigm(float x) { return 1.f / (1.f + __expf(-x)); }
__device__ __forceinline__ float tanh_(float x) { return 2.f / (1.f + __expf(-2.f * x)) - 1.f; }
__device__ __forceinline__ float wred(float v) {
#pragma unroll
  for (int off = 32; off; off >>= 1) v += __shfl_xor(v, off, 64);
  return v;
}
// agent-scope (device-coherent) accesses: bypass non-coherent per-XCD L2.
__device__ __forceinline__ void cstoref(float* p, float v) {
  __hip_atomic_store(p, v, __ATOMIC_RELAXED, __HIP_MEMORY_SCOPE_AGENT);
}
__device__ __forceinline__ float cloadf(const float* p) {
  return __hip_atomic_load(p, __ATOMIC_RELAXED, __HIP_MEMORY_SCOPE_AGENT);
}
__device__ __forceinline__ void cstoreu(unsigned* p, unsigned v) {
  __hip_atomic_store(p, v, __ATOMIC_RELAXED, __HIP_MEMORY_SCOPE_AGENT);
}
__device__ __forceinline__ unsigned long long cload64(const unsigned long long* p) {
  return __hip_atomic_load(p, __ATOMIC_RELAXED, __HIP_MEMORY_SCOPE_AGENT);
}
__device__ __forceinline__ void cstore64(unsigned long long* p, unsigned long long v) {
  __hip_atomic_store(p, v, __ATOMIC_RELAXED, __HIP_MEMORY_SCOPE_AGENT);
}

// Tree barrier (4 uses: setup x2, latents x2). 32B-spaced counters at ws+0.
__device__ __forceinline__ void gbar_tree(unsigned* tree, int idx, unsigned e) {
  const int ls = 8;
  __syncthreads();
  if (threadIdx.x == 0) {
    unsigned* leaf = tree + (idx >> 3) * ls;
    unsigned* root = tree + 32 * ls;
    unsigned* flag = root + ls;
    unsigned old = __hip_atomic_fetch_add(leaf, 1u, __ATOMIC_RELAXED, __HIP_MEMORY_SCOPE_AGENT);
    if (old == e * 8u - 1u) {
      unsigned ro = __hip_atomic_fetch_add(root, 1u, __ATOMIC_RELAXED, __HIP_MEMORY_SCOPE_AGENT);
      if (ro == e * 32u - 1u)
        __hip_atomic_store(flag, e, __ATOMIC_RELAXED, __HIP_MEMORY_SCOPE_AGENT);
    }
    while (__hip_atomic_load(flag, __ATOMIC_RELAXED, __HIP_MEMORY_SCOPE_AGENT) < e)
      __builtin_amdgcn_s_sleep(2);
  }
  __syncthreads();
}

__global__ __launch_bounds__(NT, 2) void rnn2_kernel(KArgs a) {
  __shared__ float smem[16384];  // 64 KB, reused per phase
  const int tid = threadIdx.x;
  const int b = blockIdx.x;
  const int wq = __builtin_amdgcn_readfirstlane(tid >> 6);
  const int lane = tid & 63;

  float* out_recf = a.out + 1280;
  float* out_recr = a.out + 1280 + 262144;
  float* out_embf = a.out + 1280 + 2 * 262144;
  float* out_embr = a.out + 1280 + 3 * 262144;

  // ================= phase 0a =================
  for (int i = tid; i < 2048; i += NT) smem[i] = a.emb[i];
  __syncthreads();
  {  // d1[dir][row] = start_vec @ Wih.T + bih + bhh   (dir0: emb[0], dir1: emb[1])
    int wg = b * 8 + wq;
#pragma unroll 1
    for (int rr = 0; rr < 4; rr++) {
      int idx = wg + rr * 2048;
      int dir = idx >> 12;
      int row = idx & 4095;
      const float* Wih = a.recWih[dir];
      const float* sv = &smem[dir * 1024];
      float acc = 0.f;
#pragma unroll
      for (int kc = 0; kc < 4; kc++) {
        int k = kc * 256 + lane * 4;
        float4 wv = *(const float4*)&Wih[row * 1024 + k];
        float4 ev = *(const float4*)&sv[k];
        acc += wv.x * ev.x + wv.y * ev.y + wv.z * ev.z + wv.w * ev.w;
      }
      acc = wred(acc);
      if (lane == 0)
        cstoref(&a.d1[dir * 4096 + row], acc + a.recBih[dir][row] + a.recBhh[dir][row]);
    }
  }
  const int gtid = b * NT + tid;
  const int GSZ = NB * NT;
  for (int i = gtid; i < 256 * 1024; i += GSZ) {
    int t = i >> 10, e = i & 1023;
    float v = a.emb[a.x[t] * 1024 + e];
    cstoref(&a.embf[i], v);
    out_embf[i] = v;
    out_embr[(255 - t) * 1024 + e] = v;
  }
  if (gtid < 1024) {
    int e = gtid;
    out_recf[e] = a.emb[1024 + e];
    out_recf[255 * 1024 + e] = a.emb[e];
    out_recr[e] = a.emb[e];
    out_recr[255 * 1024 + e] = a.emb[1024 + e];
  }
  if (gtid < 4096) cstore64(&a.hTenc[gtid], packtag(0u, 0.f));  // h0=c0=0, tag 0
  if (gtid < 8192) {
    int dir = gtid >> 12, r = gtid & 4095;
    cstoref(&a.bsum[gtid], a.recBih[dir][r] + a.recBhh[dir][r]);
  }
  if (a.fast) {
    unsigned* W32 = (unsigned*)a.WhhE;
    const int N4 = 8192 * 2048 / 4;
    for (int i = gtid; i < N4; i += GSZ) {
      float4 v = *(const float4*)&a.encWhh[(size_t)i * 4];
      cstoreu(&W32[i * 2], packh2(v.x, v.y));
      cstoreu(&W32[i * 2 + 1], packh2(v.z, v.w));
    }
    unsigned* C32 = (unsigned*)a.Wcomb;
    const int M4 = 4096 * 1024 / 4;
    for (int i = gtid; i < 2 * M4; i += GSZ) {
      int dir = (i >= M4) ? 1 : 0;
      int j = i - dir * M4;
      float4 va = *(const float4*)&a.recWih[dir][(size_t)j * 4];
      float4 vb = *(const float4*)&a.recWhh[dir][(size_t)j * 4];
      cstoreu(&C32[(size_t)dir * (M4 * 2) + j * 2], packh2(va.x + vb.x, va.y + vb.y));
      cstoreu(&C32[(size_t)dir * (M4 * 2) + j * 2 + 1], packh2(va.z + vb.z, va.w + vb.w));
    }
  }
  gbar_tree(a.barFull, b, 1u);

  // ================= phase 0b: P GEMM =================
  {
    const int tdb = b & 7;
    const int rb = (b >> 3) * 256;
    const int td = tdb * 64 + lane;
    const int dirc = td >> 8;
    const int tcol = td & 255;
    float acc[2][16];
#pragma unroll
    for (int p = 0; p < 2; p++)
#pragma unroll
      for (int r = 0; r < 16; r++) acc[p][r] = 0.f;
    const int s_td = tid >> 3;
    const int s_j = tid & 7;
    int std_ = tdb * 64 + s_td;
    int st = std_ & 255;
    const float* s_esrc = &a.embf[((std_ >> 8) ? (255 - st) : st) * 1024];
#pragma unroll 1
    for (int kc = 0; kc < 4; kc++) {
      __syncthreads();
#pragma unroll
      for (int m = 0; m < 8; m++) {
        int kk = s_j * 32 + m * 4;
        float4 v = *(const float4*)&s_esrc[kc * 256 + kk];
        smem[(kk + 0) * 64 + s_td] = v.x;
        smem[(kk + 1) * 64 + s_td] = v.y;
        smem[(kk + 2) * 64 + s_td] = v.z;
        smem[(kk + 3) * 64 + s_td] = v.w;
      }
      __syncthreads();
#pragma unroll
      for (int p = 0; p < 2; p++) {
        int row0 = rb + wq * 32 + p * 16;
#pragma unroll 1
        for (int k4 = 0; k4 < 64; k4++) {
          float e0 = smem[(k4 * 4 + 0) * 64 + lane];
          float e1 = smem[(k4 * 4 + 1) * 64 + lane];
          float e2 = smem[(k4 * 4 + 2) * 64 + lane];
          float e3 = smem[(k4 * 4 + 3) * 64 + lane];
#pragma unroll
          for (int r = 0; r < 16; r++) {
            const float* wp = &a.encWih[(size_t)(row0 + r) * 1024 + kc * 256 + k4 * 4];
            float w0 = wp[0], w1 = wp[1], w2 = wp[2], w3 = wp[3];
            acc[p][r] = fmaf(e0, w0, fmaf(e1, w1, fmaf(e2, w2, fmaf(e3, w3, acc[p][r]))));
          }
        }
      }
    }
#pragma unroll
    for (int p = 0; p < 2; p++)
#pragma unroll
      for (int r = 0; r < 16; r++) {
        int row = rb + wq * 32 + p * 16 + r;
        float bias = a.encBih[row] + a.encBhh[row];
        cstoref(&a.P[(size_t)(dirc * 8192 + row) * 256 + tcol], acc[p][r] + bias);
      }
  }
  gbar_tree(a.barFull, b, 2u);

  // ================= encoder: 256 steps, tagged exchange (HW-proven) =====
  {
    const int u = b * 8 + wq;
    float wreg[128];  // VGPR-resident Whh slice: 4 gates x 2048 k (32 k/lane)
    if (a.fast) {
      const unsigned long long* W64 = (const unsigned long long*)a.WhhE;
#pragma unroll
      for (int g = 0; g < 4; g++)
#pragma unroll
        for (int c = 0; c < 8; c++) {
          unsigned long long w = cload64(&W64[(size_t)(g * 2048 + u) * 512 + c * 64 + lane]);
          float2 f01 = h2f2((unsigned)w), f23 = h2f2((unsigned)(w >> 32));
          wreg[(g * 8 + c) * 4 + 0] = f01.x;
          wreg[(g * 8 + c) * 4 + 1] = f01.y;
          wreg[(g * 8 + c) * 4 + 2] = f23.x;
          wreg[(g * 8 + c) * 4 + 3] = f23.y;
        }
    }
    float cf = 0.f, cr = 0.f;
#pragma unroll 1
    for (int t = 0; t < 256; t++) {
      float pf[4], pr[4];  // issue early: latency hides behind the poll
#pragma unroll
      for (int g = 0; g < 4; g++) {
        pf[g] = cloadf(&a.P[(size_t)(g * 2048 + u) * 256 + t]);
        pr[g] = cloadf(&a.P[(size_t)(8192 + g * 2048 + u) * 256 + t]);
      }
      {  // poll-stage tagged h (4096 elems, 8/thread, coalesced)
        const unsigned long long* src = a.hTenc + (t & 1) * 4096;
        const unsigned tg = (unsigned)t;
        unsigned long long v[8];
        for (;;) {
#pragma unroll
          for (int j = 0; j < 8; j++) v[j] = cload64(&src[j * 512 + tid]);
          unsigned bad = 0;
#pragma unroll
          for (int j = 0; j < 8; j++) bad |= ((unsigned)(v[j] >> 32)) ^ tg;
          if (!bad) break;
          __builtin_amdgcn_s_sleep(1);
        }
#pragma unroll
        for (int j = 0; j < 8; j++) smem[j * 512 + tid] = __uint_as_float((unsigned)v[j]);
      }
      __syncthreads();
      float af[4] = {0, 0, 0, 0}, ar[4] = {0, 0, 0, 0};
      if (a.fast) {
#pragma unroll
        for (int c = 0; c < 8; c++) {
          float4 hf = *(const float4*)&smem[c * 256 + lane * 4];
          float4 hr = *(const float4*)&smem[2048 + c * 256 + lane * 4];
#pragma unroll
          for (int g = 0; g < 4; g++) {
            const int wb = (g * 8 + c) * 4;
            af[g] = fmaf(wreg[wb + 0], hf.x, fmaf(wreg[wb + 1], hf.y,
                    fmaf(wreg[wb + 2], hf.z, fmaf(wreg[wb + 3], hf.w, af[g]))));
            ar[g] = fmaf(wreg[wb + 0], hr.x, fmaf(wreg[wb + 1], hr.y,
                    fmaf(wreg[wb + 2], hr.z, fmaf(wreg[wb + 3], hr.w, ar[g]))));
          }
        }
      } else {
#pragma unroll 1
        for (int kc = 0; kc < 8; kc++) {
          int k = kc * 256 + lane * 4;
          float4 hf = *(const float4*)&smem[k];
          float4 hr = *(const float4*)&smem[2048 + k];
#pragma unroll
          for (int g = 0; g < 4; g++) {
            float4 wv = *(const float4*)&a.encWhh[(size_t)(g * 2048 + u) * 2048 + k];
            af[g] += wv.x * hf.x + wv.y * hf.y + wv.z * hf.z + wv.w * hf.w;
            ar[g] += wv.x * hr.x + wv.y * hr.y + wv.z * hr.z + wv.w * hr.w;
          }
        }
      }
#pragma unroll
      for (int g = 0; g < 4; g++) { af[g] = wred(af[g]); ar[g] = wred(ar[g]); }
      float gi = af[0] + pf[0], gf = af[1] + pf[1], gg = af[2] + pf[2], go = af[3] + pf[3];
      cf = sigm(gf) * cf + sigm(gi) * tanh_(gg);
      float hfv = sigm(go) * tanh_(cf);
      gi = ar[0] + pr[0]; gf = ar[1] + pr[1]; gg = ar[2] + pr[2]; go = ar[3] + pr[3];
      cr = sigm(gf) * cr + sigm(gi) * tanh_(gg);
      float hrv = sigm(go) * tanh_(cr);
      if (lane == 0) {  // fire-and-forget tagged store; consumers poll
        unsigned long long* dst = a.hTenc + ((t + 1) & 1) * 4096;
        cstore64(&dst[u], packtag((unsigned)(t + 1), hfv));
        cstore64(&dst[2048 + u], packtag((unsigned)(t + 1), hrv));
      }
      __syncthreads();  // protect smem before next iteration's staging
    }
  }

  // ================= latents: tree-barrier sequenced (R6) =================
  if (b <= 192) {
    {  // stage final h (buf0, tag 256)
      const unsigned long long* src = a.hTenc;
      unsigned long long v[8];
      for (;;) {
#pragma unroll
        for (int j = 0; j < 8; j++) v[j] = cload64(&src[j * 512 + tid]);
        unsigned bad = 0;
#pragma unroll
        for (int j = 0; j < 8; j++) bad |= ((unsigned)(v[j] >> 32)) ^ 256u;
        if (!bad) break;
        __builtin_amdgcn_s_sleep(1);
      }
#pragma unroll
      for (int j = 0; j < 8; j++) smem[j * 512 + tid] = __uint_as_float((unsigned)v[j]);
    }
    __syncthreads();
    int wg = b * 8 + wq;
    if (wg < 512) {  // common row
      int r = wg;
      float acc = 0.f;
#pragma unroll 1
      for (int kc = 0; kc < 16; kc++) {
        int k = kc * 256 + lane * 4;
        float4 wv = *(const float4*)&a.clsW[(size_t)r * 4096 + k];
        float4 hv = *(const float4*)&smem[k];
        acc += wv.x * hv.x + wv.y * hv.y + wv.z * hv.z + wv.w * hv.w;
      }
      acc = wred(acc);
      if (lane == 0) cstoref(&a.common[r], tanh_(acc + a.clsB[r]));
    } else if (wg < 1024) {  // lat_f
      int r = wg - 512;
      float acc = 0.f;
#pragma unroll 1
      for (int kc = 0; kc < 8; kc++) {
        int k = kc * 256 + lane * 4;
        float4 wv = *(const float4*)&a.latfW[(size_t)r * 2048 + k];
        float4 hv = *(const float4*)&smem[k];
        acc += wv.x * hv.x + wv.y * hv.y + wv.z * hv.z + wv.w * hv.w;
      }
      acc = wred(acc);
      if (lane == 0) {
        float v = acc + a.latfB[r];
        cstore64(&a.hTdec[64 + r], packtag(0u, v));
        a.out[64 + r] = v;
      }
    } else if (wg < 1536) {  // lat_r
      int r = wg - 1024;
      float acc = 0.f;
#pragma unroll 1
      for (int kc = 0; kc < 8; kc++) {
        int k = kc * 256 + lane * 4;
        float4 wv = *(const float4*)&a.latrW[(size_t)r * 2048 + k];
        float4 hv = *(const float4*)&smem[2048 + k];
        acc += wv.x * hv.x + wv.y * hv.y + wv.z * hv.z + wv.w * hv.w;
      }
      acc = wred(acc);
      if (lane == 0) {
        float v = acc + a.latrB[r];
        cstore64(&a.hTdec[1024 + 64 + r], packtag(0u, v));
        a.out[640 + 64 + r] = v;
      }
    } else if (wg == 1536) {  // vg
      float v = a.embVg[a.Vg[0] * 64 + lane];
      cstore64(&a.hTdec[lane], packtag(0u, v));
      cstore64(&a.hTdec[1024 + lane], packtag(0u, v));
      a.out[lane] = v;
      a.out[640 + lane] = v;
    } else if (wg == 1537) {  // jg
      float v = a.embJg[a.Jg[0] * 64 + lane];
      cstore64(&a.hTdec[576 + lane], packtag(0u, v));
      cstore64(&a.hTdec[1024 + 576 + lane], packtag(0u, v));
      a.out[576 + lane] = v;
      a.out[640 + 576 + lane] = v;
    }
  }
  gbar_tree(a.barFull, b, 3u);  // common + lat + vg/jg complete, grid-wide
  if (b < 48) {  // mix rows 0..383
    int wg = b * 8 + wq;
    smem[tid] = cloadf(&a.common[tid]);  // 512 threads, 512 entries
    __syncthreads();
    float acc = 0.f;
#pragma unroll
    for (int kc = 0; kc < 2; kc++) {
      int k = kc * 256 + lane * 4;
      float4 wv = *(const float4*)&a.mixW[(size_t)wg * 512 + k];
      float4 hv = *(const float4*)&smem[k];
      acc += wv.x * hv.x + wv.y * hv.y + wv.z * hv.z + wv.w * hv.w;
    }
    acc = wred(acc);
    if (lane == 0) {
      float v = acc + a.mixB[wg];
      cstore64(&a.hTdec[640 + wg], packtag(0u, v));
      cstore64(&a.hTdec[1024 + 640 + wg], packtag(0u, v));
    }
  }
  gbar_tree(a.barFull, b, 4u);  // full h0 (tag 0) in hTdec, grid-wide

  // ================= decoders: 254 steps, tagged exchange =================
  {
    const int dir = b & 1;
    const int hidx = b >> 1;
    const int u = hidx * 8 + wq;
    float* outrec = dir ? out_recr : out_recf;
    float bs[4];
#pragma unroll
    for (int g = 0; g < 4; g++) bs[g] = cloadf(&a.bsum[dir * 4096 + g * 1024 + u]);
    float wd[64];  // VGPR-resident Wcomb slice: 4 gates x 1024 k (16 k/lane)
    if (a.fast) {
      const unsigned long long* C64 = (const unsigned long long*)a.Wcomb;
      const size_t dbase = (size_t)dir * (4096 * 1024 / 4);
#pragma unroll
      for (int g = 0; g < 4; g++)
#pragma unroll
        for (int c = 0; c < 4; c++) {
          unsigned long long w = cload64(&C64[dbase + (size_t)(g * 1024 + u) * 256 + c * 64 + lane]);
          float2 f01 = h2f2((unsigned)w), f23 = h2f2((unsigned)(w >> 32));
          wd[(g * 4 + c) * 4 + 0] = f01.x;
          wd[(g * 4 + c) * 4 + 1] = f01.y;
          wd[(g * 4 + c) * 4 + 2] = f23.x;
          wd[(g * 4 + c) * 4 + 3] = f23.y;
        }
    }
    float c = 0.f;
#pragma unroll 1
    for (int s = 1; s <= 254; s++) {
      {  // poll-stage tagged h (1024 elems, 2/thread)
        const unsigned long long* src = a.hTdec + ((s - 1) & 1) * 2048 + dir * 1024;
        const unsigned tg = (unsigned)(s - 1);
        unsigned long long v0, v1;
        for (;;) {
          v0 = cload64(&src[tid]);
          v1 = cload64(&src[512 + tid]);
          if ((((unsigned)(v0 >> 32)) ^ tg) == 0u && (((unsigned)(v1 >> 32)) ^ tg) == 0u) break;
          __builtin_amdgcn_s_sleep(1);
        }
        smem[tid] = __uint_as_float((unsigned)v0);
        smem[512 + tid] = __uint_as_float((unsigned)v1);
      }
      __syncthreads();
      float acc[4] = {0, 0, 0, 0};
      if (s == 1) {  // g = d1 + h0 @ Whh.T  (f32 weights, one step)
        const float* Whh = a.recWhh[dir];
#pragma unroll 1
        for (int kc = 0; kc < 4; kc++) {
          int k = kc * 256 + lane * 4;
          float4 hv = *(const float4*)&smem[k];
#pragma unroll
          for (int g = 0; g < 4; g++) {
            float4 wv = *(const float4*)&Whh[(size_t)(g * 1024 + u) * 1024 + k];
            acc[g] += wv.x * hv.x + wv.y * hv.y + wv.z * hv.z + wv.w * hv.w;
          }
        }
      } else if (a.fast) {
#pragma unroll
        for (int cc = 0; cc < 4; cc++) {
          float4 hv = *(const float4*)&smem[cc * 256 + lane * 4];
#pragma unroll
          for (int g = 0; g < 4; g++) {
            const int wb = (g * 4 + cc) * 4;
            acc[g] = fmaf(wd[wb + 0], hv.x, fmaf(wd[wb + 1], hv.y,
                     fmaf(wd[wb + 2], hv.z, fmaf(wd[wb + 3], hv.w, acc[g]))));
          }
        }
      } else {
        const float* Wi = a.recWih[dir];
        const float* Wh = a.recWhh[dir];
#pragma unroll 1
        for (int kc = 0; kc < 4; kc++) {
          int k = kc * 256 + lane * 4;
          float4 hv = *(const float4*)&smem[k];
#pragma unroll
          for (int g = 0; g < 4; g++) {
            size_t ro = (size_t)(g * 1024 + u) * 1024 + k;
            float4 va = *(const float4*)&Wi[ro];
            float4 vb = *(const float4*)&Wh[ro];
            acc[g] += (va.x + vb.x) * hv.x + (va.y + vb.y) * hv.y +
                      (va.z + vb.z) * hv.z + (va.w + vb.w) * hv.w;
          }
        }
      }
#pragma unroll
      for (int g = 0; g < 4; g++) acc[g] = wred(acc[g]);
      float gi, gf, gg, go;
      if (s == 1) {
        gi = acc[0] + cloadf(&a.d1[dir * 4096 + u]);
        gf = acc[1] + cloadf(&a.d1[dir * 4096 + 1024 + u]);
        gg = acc[2] + cloadf(&a.d1[dir * 4096 + 2048 + u]);
        go = acc[3] + cloadf(&a.d1[dir * 4096 + 3072 + u]);
        c = smem[u];  // c0 = h0
      } else {
        gi = acc[0] + bs[0]; gf = acc[1] + bs[1]; gg = acc[2] + bs[2]; go = acc[3] + bs[3];
      }
      c = sigm(gf) * c + sigm(gi) * tanh_(gg);
      float h2 = sigm(go) * tanh_(c);
      if (lane == 0) {
        outrec[(size_t)(255 - s) * 1024 + u] = h2;
        if (s < 254)
          cstore64(&a.hTdec[(s & 1) * 2048 + dir * 1024 + u], packtag((unsigned)s, h2));
      }
      __syncthreads();
    }
  }
}

extern "C" void kernel_launch(void* const* d_in, const int* in_sizes, int n_in,
                              void* d_out, int out_size, void* d_ws, size_t ws_size,
                              hipStream_t stream) {
  (void)in_sizes; (void)n_in; (void)out_size;
  KArgs a;
  a.x = (const int*)d_in[0];
  a.Vg = (const int*)d_in[1];
  a.Jg = (const int*)d_in[2];
  a.emb = (const float*)d_in[3];
  a.embVg = (const float*)d_in[4];
  a.embJg = (const float*)d_in[5];
  a.encWih = (const float*)d_in[6];
  a.encWhh = (const float*)d_in[7];
  a.encBih = (const float*)d_in[8];
  a.encBhh = (const float*)d_in[9];
  a.clsW = (const float*)d_in[10];
  a.clsB = (const float*)d_in[11];
  a.latfW = (const float*)d_in[12];
  a.latfB = (const float*)d_in[13];
  a.latrW = (const float*)d_in[14];
  a.latrB = (const float*)d_in[15];
  a.mixW = (const float*)d_in[16];
  a.mixB = (const float*)d_in[17];
  a.recWih[0] = (const float*)d_in[18];
  a.recWhh[0] = (const float*)d_in[19];
  a.recBih[0] = (const float*)d_in[20];
  a.recBhh[0] = (const float*)d_in[21];
  a.recWih[1] = (const float*)d_in[22];
  a.recWhh[1] = (const float*)d_in[23];
  a.recBih[1] = (const float*)d_in[24];
  a.recBhh[1] = (const float*)d_in[25];
  a.out = (float*)d_out;
  char* ws = (char*)d_ws;
  a.barFull = (unsigned*)ws;
  a.hTenc = (unsigned long long*)(ws + 4096);
  a.hTdec = (unsigned long long*)(ws + 69632);
  a.common = (float*)(ws + 86016);
  a.bsum = (float*)(ws + 90112);
  a.d1 = (float*)(ws + 122880);
  a.embf = (float*)(ws + 155648);
  a.P = (float*)(ws + 1204224);
  a.Wcomb = (unsigned short*)(ws + 17981440);
  a.WhhE = (unsigned short*)(ws + 34758656);
  a.fast = (ws_size >= 68313088ULL) ? 1 : 0;
  hipMemsetAsync(ws, 0, 4096, stream);  // zero tree-barrier counters only
  hipLaunchKernelGGL(rnn2_kernel, dim3(NB), dim3(NT), 0, stream, a);
}